// Round 7
// baseline (89.838 us; speedup 1.0000x reference)
//
#include <hip/hip_runtime.h>
#include <math.h>

// Problem constants (match reference)
#define B_ 2
#define T_ 2048
#define M_ 768
#define R_ 64
#define S_ 16
#define MS_ (M_ * S_)
#define NC 64
#define CL 32              // T_ / NC
#define LOG_EPS_F (-23.025850929940457f)

// --------------------------------------------------------------------------
// Kernel 1 (bc v6, round-5 verified): register-cached W. Wave holds 4 s-rows
// of W (48 VGPR) and processes 8 bt rows (acc[32] = 8 rows x 4 s).
// Block = 512 thr / 8 waves covering all 32 s. Fold+pack butterfly reduce.
// --------------------------------------------------------------------------
__global__ __launch_bounds__(512, 4) void bc_kernel(
    const float* __restrict__ u,     // [B*T][M]
    const float* __restrict__ B_w,   // [S][M]
    const float* __restrict__ C_w,   // [S][M]
    float* __restrict__ Bm,          // [B*T][S]
    float* __restrict__ Cm)          // [B*T][S]
{
  const int wave = threadIdx.x >> 6, lane = threadIdx.x & 63;
  const int bt0 = blockIdx.x * 8;

  float4 w[4][3];
  #pragma unroll
  for (int s = 0; s < 4; ++s) {
    const int s_g = wave * 4 + s;
    const float* wr = (s_g < 16) ? &B_w[(size_t)s_g * M_] : &C_w[(size_t)(s_g - 16) * M_];
    const float4* w4 = reinterpret_cast<const float4*>(wr);
    w[s][0] = w4[lane]; w[s][1] = w4[64 + lane]; w[s][2] = w4[128 + lane];
  }

  float acc[32];
  #pragma unroll
  for (int r = 0; r < 8; ++r) {
    const float4* ur = reinterpret_cast<const float4*>(&u[(size_t)(bt0 + r) * M_]);
    const float4 a0 = ur[lane], a1 = ur[64 + lane], a2 = ur[128 + lane];
    #pragma unroll
    for (int s = 0; s < 4; ++s) {
      float t = 0.f;
      t = fmaf(a0.x, w[s][0].x, t); t = fmaf(a0.y, w[s][0].y, t);
      t = fmaf(a0.z, w[s][0].z, t); t = fmaf(a0.w, w[s][0].w, t);
      t = fmaf(a1.x, w[s][1].x, t); t = fmaf(a1.y, w[s][1].y, t);
      t = fmaf(a1.z, w[s][1].z, t); t = fmaf(a1.w, w[s][1].w, t);
      t = fmaf(a2.x, w[s][2].x, t); t = fmaf(a2.y, w[s][2].y, t);
      t = fmaf(a2.z, w[s][2].z, t); t = fmaf(a2.w, w[s][2].w, t);
      acc[r * 4 + s] = t;
    }
  }

  #pragma unroll
  for (int j = 0; j < 32; ++j) acc[j] += __shfl_xor(acc[j], 32);
  int cnt = 32;
  #pragma unroll
  for (int mask = 16; mask >= 1; mask >>= 1) {
    cnt >>= 1;
    const bool up = (lane & mask) != 0;
    #pragma unroll
    for (int j = 0; j < cnt; ++j) {
      float give = up ? acc[j] : acc[j + cnt];
      float keep = up ? acc[j + cnt] : acc[j];
      acc[j] = keep + __shfl_xor(give, mask);
    }
  }

  if (lane < 32) {
    const int r = lane >> 2, s_l = lane & 3;
    const int s_g = wave * 4 + s_l;
    const int bt = bt0 + r;
    if (s_g < 16) Bm[(size_t)bt * S_ + s_g] = acc[0];
    else          Cm[(size_t)bt * S_ + (s_g - 16)] = acc[0];
  }
}

// --------------------------------------------------------------------------
// Kernels 2 & 4: fused dt-GEMM + chunk-local scan. Block = (b, chunk, m-tile
// of 64), 128 thr (2 waves = 64 m x 2 s-halves). dt is computed IN-KERNEL
// into LDS (never touches HBM): delta tile staged coalesced, dt_w rows read
// from L2. PHASE 1: h_in=0, write P/Hend. PHASE 3: h_in=carry, write out.
// Summaries [B][NC][S][M] coalesced per m. LDS ~25 KB -> 6 blocks/CU.
// --------------------------------------------------------------------------
#define DPITCH 72   // delta_s row pitch (288 B, 16B-aligned rows)

template <int PHASE>
__global__ __launch_bounds__(128) void scan_fused(
    const float* __restrict__ u,       // [B*T][M]
    const float* __restrict__ delta,   // [B*T][R]
    const float* __restrict__ dt_w,    // [M][R]
    const float* __restrict__ dt_b,    // [M]
    const float* __restrict__ Bm,      // [B*T][S]
    const float* __restrict__ Cm,      // [B*T][S]
    const float* __restrict__ A_log,   // [S][M]
    const float* __restrict__ D,       // [M]
    float* __restrict__ Aprod,         // [B][NC][S][M]; carry after kernel 3
    float* __restrict__ Hend,          // [B][NC][S][M]
    float* __restrict__ out)           // [B*T][M]
{
  __shared__ float u_lds[CL][64];
  __shared__ float dt_lds[CL][64];
  __shared__ float scratch[CL * DPITCH];   // delta_s; later bm[512]|cm[512]

  const int tid = threadIdx.x;
  const int mt = blockIdx.x;               // 0..11
  const int c  = blockIdx.y;               // 0..63
  const int b  = blockIdx.z;
  const int m0 = mt * 64;
  const int t0 = c * CL;
  const size_t row0 = (size_t)b * T_ + t0;

  // ---- stage delta [CL][64] (pitch 72) + u [CL][64], coalesced float4 ----
  {
    float (*delta_s)[DPITCH] = reinterpret_cast<float (*)[DPITCH]>(scratch);
    #pragma unroll
    for (int p = 0; p < 4; ++p) {
      const int i4 = tid + p * 128;        // 512 float4
      const int t = i4 >> 4, c4 = (i4 & 15) * 4;
      *reinterpret_cast<float4*>(&delta_s[t][c4]) =
          *reinterpret_cast<const float4*>(&delta[(row0 + t) * R_ + c4]);
      *reinterpret_cast<float4*>(&u_lds[t][c4]) =
          *reinterpret_cast<const float4*>(&u[(row0 + t) * M_ + m0 + c4]);
    }
  }
  __syncthreads();

  // ---- dt tile: clip(softplus(delta . dt_w[m]^T + b)) -> dt_lds ----
  {
    float (*delta_s)[DPITCH] = reinterpret_cast<float (*)[DPITCH]>(scratch);
    const int ml2 = tid & 63, th = tid >> 6;   // thread: m=m0+ml2, t-half th
    float acc[16] = {};
    const float* wrow = &dt_w[(size_t)(m0 + ml2) * R_];
    #pragma unroll
    for (int r4 = 0; r4 < R_; r4 += 4) {
      const float4 w4 = *reinterpret_cast<const float4*>(&wrow[r4]);
      #pragma unroll
      for (int i = 0; i < 16; ++i) {
        const float4 d4 = *reinterpret_cast<const float4*>(&delta_s[th * 16 + i][r4]);
        acc[i] = fmaf(d4.x, w4.x, acc[i]);
        acc[i] = fmaf(d4.y, w4.y, acc[i]);
        acc[i] = fmaf(d4.z, w4.z, acc[i]);
        acc[i] = fmaf(d4.w, w4.w, acc[i]);
      }
    }
    const float bias = dt_b[m0 + ml2];
    #pragma unroll
    for (int i = 0; i < 16; ++i) {
      const float x = acc[i] + bias;
      const float sp = (x > 20.f) ? x : __logf(1.f + __expf(x));
      dt_lds[th * 16 + i][ml2] = fminf(fmaxf(sp, 1e-6f), 10.f);
    }
  }
  __syncthreads();   // delta_s dead

  // ---- stage bm/cm into scratch; compute Acol ----
  float* bm_lds = scratch;            // [CL][16]
  float* cm_lds = scratch + CL * S_;
  {
    const size_t bcb = row0 * S_;
    #pragma unroll
    for (int p = 0; p < CL * S_ / 128; ++p) {
      const int idx = tid + p * 128;
      bm_lds[idx] = Bm[bcb + idx];
      if constexpr (PHASE == 3) cm_lds[idx] = Cm[bcb + idx];
    }
  }

  const int lane = tid & 63, wv = tid >> 6;
  const int m_l = wv * 32 + (lane & 31);     // 0..63
  const int sh = lane >> 5, s0 = sh * 8;
  const int m = m0 + m_l;

  float Acol[8];
  #pragma unroll
  for (int s = 0; s < 8; ++s) {
    const float a = -__expf(A_log[(size_t)(s0 + s) * M_ + m]);
    Acol[s] = fminf(fmaxf(a, -10.f), -1e-6f);
  }

  float h[8], P[8], Dm = 0.f;
  const size_t smb = (((size_t)b * NC + c) * S_ + s0) * M_ + m;
  if constexpr (PHASE == 1) {
    #pragma unroll
    for (int s = 0; s < 8; ++s) { h[s] = 0.f; P[s] = 1.f; }
  } else {
    #pragma unroll
    for (int s = 0; s < 8; ++s) h[s] = Aprod[smb + (size_t)s * M_];  // carry
    Dm = D[m];
  }
  __syncthreads();

  // ---- serial recurrence over the chunk (LDS-only operands) ----
  #pragma unroll 8
  for (int t = 0; t < CL; ++t) {
    const float dtv = dt_lds[t][m_l];
    const float uv  = u_lds[t][m_l];
    const float du  = dtv * uv;
    const float4 bv0 = *reinterpret_cast<const float4*>(&bm_lds[t * S_ + s0]);
    const float4 bv1 = *reinterpret_cast<const float4*>(&bm_lds[t * S_ + s0 + 4]);
    const float bmv[8] = {bv0.x, bv0.y, bv0.z, bv0.w, bv1.x, bv1.y, bv1.z, bv1.w};
    float cmv[8];
    if constexpr (PHASE == 3) {
      const float4 cv0 = *reinterpret_cast<const float4*>(&cm_lds[t * S_ + s0]);
      const float4 cv1 = *reinterpret_cast<const float4*>(&cm_lds[t * S_ + s0 + 4]);
      cmv[0] = cv0.x; cmv[1] = cv0.y; cmv[2] = cv0.z; cmv[3] = cv0.w;
      cmv[4] = cv1.x; cmv[5] = cv1.y; cmv[6] = cv1.z; cmv[7] = cv1.w;
    }
    float y = 0.f;
    #pragma unroll
    for (int s = 0; s < 8; ++s) {
      const float la = fmaxf(dtv * Acol[s], LOG_EPS_F);
      const float e = __expf(la);
      h[s] = fmaf(e, h[s], du * bmv[s]);
      if constexpr (PHASE == 1) P[s] *= e;
      else y = fmaf(h[s], cmv[s], y);
    }
    if constexpr (PHASE == 3) {
      y += __shfl_xor(y, 32);
      if (sh == 0) {
        const float o = y + uv * Dm;
        out[(row0 + t) * M_ + m] = fminf(fmaxf(o, -1e4f), 1e4f);
      }
    }
  }

  if constexpr (PHASE == 1) {
    #pragma unroll
    for (int s = 0; s < 8; ++s) {
      Aprod[smb + (size_t)s * M_] = P[s];
      Hend[smb + (size_t)s * M_]  = h[s];
    }
  }
}

// --------------------------------------------------------------------------
// Kernel 3: chunk-carry combine, in place: Aprod[c] is read (decay product)
// then overwritten with the carry (h-state entering chunk c).
// --------------------------------------------------------------------------
__global__ __launch_bounds__(256) void carry_kernel(
    float* __restrict__ Aprod, const float* __restrict__ Hend)
{
  const int idx = blockIdx.x * 256 + threadIdx.x;  // over B*S*M
  const int b = idx / MS_;
  const int sm = idx - b * MS_;
  float h = 0.f;
  #pragma unroll 16
  for (int c = 0; c < NC; ++c) {
    const size_t o = ((size_t)b * NC + c) * MS_ + sm;
    const float a  = Aprod[o];
    const float he = Hend[o];
    Aprod[o] = h;                 // carry into chunk c
    h = fmaf(a, h, he);
  }
}

// --------------------------------------------------------------------------
extern "C" void kernel_launch(void* const* d_in, const int* in_sizes, int n_in,
                              void* d_out, int out_size, void* d_ws, size_t ws_size,
                              hipStream_t stream)
{
  const float* u     = (const float*)d_in[0];
  const float* delta = (const float*)d_in[1];
  const float* dt_w  = (const float*)d_in[2];
  const float* dt_b  = (const float*)d_in[3];
  const float* A_log = (const float*)d_in[4];
  const float* B_w   = (const float*)d_in[5];
  const float* C_w   = (const float*)d_in[6];
  const float* D     = (const float*)d_in[7];
  float* out = (float*)d_out;
  float* ws  = (float*)d_ws;

  const size_t fl_bc = (size_t)B_ * T_ * S_;   // 65,536
  const size_t fl_sm = (size_t)B_ * NC * MS_;  // 1,572,864

  float* Bm    = ws;
  float* Cm    = Bm + fl_bc;
  float* Aprod = Cm + fl_bc;         // later holds carries
  float* Hend  = Aprod + fl_sm;      // total ~13.1 MB

  bc_kernel<<<dim3((B_ * T_) / 8), 512, 0, stream>>>(u, B_w, C_w, Bm, Cm);
  scan_fused<1><<<dim3(M_ / 64, NC, B_), 128, 0, stream>>>(
      u, delta, dt_w, dt_b, Bm, Cm, A_log, D, Aprod, Hend, nullptr);
  carry_kernel<<<dim3((B_ * MS_) / 256), 256, 0, stream>>>(Aprod, Hend);
  scan_fused<3><<<dim3(M_ / 64, NC, B_), 128, 0, stream>>>(
      u, delta, dt_w, dt_b, Bm, Cm, A_log, D, Aprod, Hend, out);
}